// Round 5
// baseline (1004.767 us; speedup 1.0000x reference)
//
#include <hip/hip_runtime.h>

typedef _Float16 half_t;
typedef __attribute__((ext_vector_type(2))) _Float16 h2;
typedef __attribute__((ext_vector_type(8))) _Float16 half8;
typedef __attribute__((ext_vector_type(4))) float f32x4;
typedef __attribute__((ext_vector_type(8))) short short8v;
typedef unsigned short u16;
typedef unsigned int u32;

// Log2-domain scaled math: all potentials are log2 of real factors,
// E' = (1-cos)*SCALE, u' = u_real*SCALE, etc.  (round-4 verified)
#define SCALE_F     14.4269504f     /* 10*log2(e) */
#define INV_SCALE_F 0.0693147181f
#define C_MU       -9.99998523f     /* log2(1/1024+1e-8) */
#define C_NU       -9.99998523f
#define CMU17       7.00001477f     /* C_MU + 17 (rt bias fold) */
#define C_NU24      14.00001477f    /* C_NU + 24 (rt 2^17 * su 2^7 bias) */
#define SU_NUM_F    16384.1678f     /* (1/1024+1e-8) * 2^24 */
#define RT_BIAS_F   17.0f           /* keeps rt in fp16 normal range */
#define ERR_STOP_B  1.44269504f     /* 0.1 * SCALE, per-batch stop */
#define ERR_STOP_G  23.0831206f     /* fallback global stop */
#define MAX_ITER    100
#define SPIN_LIMIT  50000000LL

#if __has_builtin(__builtin_amdgcn_fdot2)
#define FDOT2(a,b,c) __builtin_amdgcn_fdot2((a),(b),(c),false)
#else
#define FDOT2(a,b,c) ((c) + (float)((a)[0]*(b)[0]) + (float)((a)[1]*(b)[1]))
#endif

__device__ __forceinline__ float fexp2(float x) { return __builtin_amdgcn_exp2f(x); }
__device__ __forceinline__ float flog2(float x) { return __builtin_amdgcn_logf(x); }
__device__ __forceinline__ float frcp(float x)  { return __builtin_amdgcn_rcpf(x); }

__device__ __forceinline__ u16 f2bf(float f) {
  unsigned u = __float_as_uint(f);
  return (u16)((u + 0x7fffu + ((u >> 16) & 1u)) >> 16);
}
__device__ __forceinline__ float bf2f(u16 h) {
  return __uint_as_float(((unsigned)h) << 16);
}

// ---------------- K1: normalize x,y -> bf16 rows; zero per-call state ------
__global__ __launch_bounds__(256) void mfa_prep(const float* __restrict__ x,
                                                const float* __restrict__ y,
                                                u16* __restrict__ Xn,
                                                u16* __restrict__ Yn,
                                                float* __restrict__ invnx,
                                                float* __restrict__ invny,
                                                float* __restrict__ errB,
                                                int* __restrict__ bars,
                                                float* __restrict__ cost) {
  int g = blockIdx.x * 256 + threadIdx.x;    // 65536 threads
  if (g < 1600) { errB[g] = 0.0f; bars[g] = 0; }
  if (g < 16)   cost[g] = 0.0f;

  int wid = g >> 6;                          // 0..1023 waves
  int lane = threadIdx.x & 63;
  for (int rr = 0; rr < 32; ++rr) {
    int row = wid + (rr << 10);              // 0..32767
    const float* src = (row < 16384) ? x + (size_t)row * 256
                                     : y + (size_t)(row - 16384) * 256;
    float4 xa = ((const float4*)src)[lane];
    float ss = xa.x*xa.x + xa.y*xa.y + xa.z*xa.z + xa.w*xa.w;
    #pragma unroll
    for (int off = 32; off; off >>= 1) ss += __shfl_xor(ss, off);
    float inv = 1.0f / fmaxf(sqrtf(ss), 1e-8f);
    ushort4 o;
    o.x = f2bf(xa.x * inv); o.y = f2bf(xa.y * inv);
    o.z = f2bf(xa.z * inv); o.w = f2bf(xa.w * inv);
    u16* dst = ((row < 16384) ? Xn + ((size_t)row << 8)
                              : Yn + ((size_t)(row - 16384) << 8)) + lane * 4;
    *(ushort4*)dst = o;
    if (lane == 0) {
      if (row < 16384) invnx[row] = inv; else invny[row - 16384] = inv;
    }
  }
}

// ---------------- K2: fused MFMA E-build + register-resident Sinkhorn ------
// 512 blocks x 256 thr, 2 blocks/CU. block: b = blk&15 (interleave so
// co-resident blocks serve different batches -> barrier spin overlaps),
// k = blk>>4 owns rows [k*32, k*32+32) of batch b. Thread owns E patch:
// rows stripe+lgrp*4+q (q=0..3), cols cbase + j*16 + lane15 (j=0..31),
// held as fp16 pairs in registers (64 VGPR) -- E never touches memory.
__global__ __launch_bounds__(256, 2) void mfa_sink_reg(
    const u16* __restrict__ Xn, const u16* __restrict__ Yn,
    u16* __restrict__ partials, float* __restrict__ errB,
    int* __restrict__ bars, float* __restrict__ cost) {
  __shared__ u16   Xs[32][264];        // bf16 A-tile, stride 264 (16B-aligned, 2-way free)
  __shared__ float vsh[1024];          // v' (log2-scaled)
  __shared__ float rowsum[32][2];      // per-row s partials (2 col-halves)
  __shared__ float cpb[2][2][512];     // colacc [col-half][row-stripe][512]
  __shared__ float sred[8];            // [0..3] werr/cost, [4] batch err

  const int t = threadIdx.x, w = t >> 6, lane = t & 63;
  const int lane15 = lane & 15, lgrp = lane >> 4;
  const int blk = blockIdx.x, b = blk & 15, k = blk >> 4;
  const int cbase = (w >> 1) << 9;     // col half: waves 0,1 -> 0; 2,3 -> 512
  const int stripe = (w & 1) << 4;     // row stripe 0 / 16

  // ---- stage A-tile (32 rows x 256 k bf16) + zero v' ----
  {
    int r = t >> 3, c0 = (t & 7) << 5;
    const u16* src = Xn + ((size_t)((b << 10) + (k << 5) + r) << 8) + c0;
    #pragma unroll
    for (int i = 0; i < 4; ++i)
      *(short8v*)&Xs[r][c0 + i * 8] = *(const short8v*)(src + i * 8);
    vsh[t] = 0.0f; vsh[t + 256] = 0.0f; vsh[t + 512] = 0.0f; vsh[t + 768] = 0.0f;
  }
  __syncthreads();

  // ---- build E' into registers via MFMA (frag mapping = round-4 verified) --
  short8v afr[8];
  #pragma unroll
  for (int ks = 0; ks < 8; ++ks)
    afr[ks] = *(const short8v*)&Xs[stripe + lane15][ks * 32 + lgrp * 8];

  h2 epk[32][2];                        // E' pairs: [j][p] = rows {lgrp*4+2p, +1}
  #pragma unroll
  for (int j = 0; j < 32; ++j) {
    f32x4 acc = (f32x4){0.f, 0.f, 0.f, 0.f};
    const u16* yrow = Yn + ((size_t)((b << 10) + cbase + (j << 4) + lane15) << 8)
                         + lgrp * 8;
    #pragma unroll
    for (int ks = 0; ks < 8; ++ks) {
      short8v bfr = *(const short8v*)(yrow + ks * 32);
      acc = __builtin_amdgcn_mfma_f32_16x16x32_bf16(afr[ks], bfr, acc, 0, 0, 0);
    }
    epk[j][0][0] = (_Float16)((1.0f - acc[0]) * SCALE_F);
    epk[j][0][1] = (_Float16)((1.0f - acc[1]) * SCALE_F);
    epk[j][1][0] = (_Float16)((1.0f - acc[2]) * SCALE_F);
    epk[j][1][1] = (_Float16)((1.0f - acc[3]) * SCALE_F);
  }

  float ur0 = 0.f, ur1 = 0.f, ur2 = 0.f, ur3 = 0.f;   // u' (registers)
  for (int it = 0; it < MAX_ITER; ++it) {
    // ---- row pass: s_q = sum_m 2^(v'+17-E'), rt cached fp16 ----
    float s0 = 0.f, s1 = 0.f, s2 = 0.f, s3 = 0.f;
    h2 rt[32][2];
    #pragma unroll
    for (int j = 0; j < 32; ++j) {
      float vj = vsh[cbase + (j << 4) + lane15] + RT_BIAS_F;
      float r0 = fexp2(vj - (float)epk[j][0][0]);
      float r1 = fexp2(vj - (float)epk[j][0][1]);
      float r2 = fexp2(vj - (float)epk[j][1][0]);
      float r3 = fexp2(vj - (float)epk[j][1][1]);
      s0 += r0; s1 += r1; s2 += r2; s3 += r3;
      rt[j][0][0] = (_Float16)r0; rt[j][0][1] = (_Float16)r1;
      rt[j][1][0] = (_Float16)r2; rt[j][1][1] = (_Float16)r3;
    }
    #pragma unroll
    for (int off = 1; off <= 8; off <<= 1) {
      s0 += __shfl_xor(s0, off); s1 += __shfl_xor(s1, off);
      s2 += __shfl_xor(s2, off); s3 += __shfl_xor(s3, off);
    }
    const int rbase = stripe + (lgrp << 2);
    if (lane15 == 0) {
      rowsum[rbase + 0][w >> 1] = s0; rowsum[rbase + 1][w >> 1] = s1;
      rowsum[rbase + 2][w >> 1] = s2; rowsum[rbase + 3][w >> 1] = s3;
    }
    __syncthreads();
    float st0 = rowsum[rbase + 0][0] + rowsum[rbase + 0][1];
    float st1 = rowsum[rbase + 1][0] + rowsum[rbase + 1][1];
    float st2 = rowsum[rbase + 2][0] + rowsum[rbase + 2][1];
    float st3 = rowsum[rbase + 3][0] + rowsum[rbase + 3][1];
    float un0 = CMU17 - flog2(st0), un1 = CMU17 - flog2(st1);
    float un2 = CMU17 - flog2(st2), un3 = CMU17 - flog2(st3);
    float werr = 0.0f;
    if (w < 2 && lane15 == 0)     // each row counted once per block
      werr = fabsf(un0-ur0) + fabsf(un1-ur1) + fabsf(un2-ur2) + fabsf(un3-ur3);
    ur0 = un0; ur1 = un1; ur2 = un2; ur3 = un3;

    h2 su01, su23;                // su' = 2^(u'+7), fp16-normal range
    su01[0] = (_Float16)(SU_NUM_F * frcp(st0));
    su01[1] = (_Float16)(SU_NUM_F * frcp(st1));
    su23[0] = (_Float16)(SU_NUM_F * frcp(st2));
    su23[1] = (_Float16)(SU_NUM_F * frcp(st3));

    // ---- col partials: dot2 over q, reduce over lgrp, stage to LDS ----
    #pragma unroll
    for (int j = 0; j < 32; ++j) {
      float c = FDOT2(rt[j][0], su01, 0.0f);
      c = FDOT2(rt[j][1], su23, c);
      c += __shfl_xor(c, 16);
      c += __shfl_xor(c, 32);
      if (lane < 16) cpb[w >> 1][w & 1][(j << 4) + lane] = c;
    }
    werr += __shfl_xor(werr, 16);
    werr += __shfl_xor(werr, 32);
    if (lane == 0) sred[w] = werr;
    __syncthreads();

    // ---- block partial (1024 cols bf16) -> global (parity dbuf) ----
    {
      int c = t << 2, h = c >> 9, cc = c & 511;
      float4 pa = *(float4*)&cpb[h][0][cc];
      float4 pb = *(float4*)&cpb[h][1][cc];
      size_t pbase = ((size_t)(((((it & 1) << 4) + b) << 5) + k)) << 10;
      uint2 st;
      st.x = (u32)f2bf(pa.x + pb.x) | ((u32)f2bf(pa.y + pb.y) << 16);
      st.y = (u32)f2bf(pa.z + pb.z) | ((u32)f2bf(pa.w + pb.w) << 16);
      *(uint2*)(partials + pbase + c) = st;
    }
    // ---- per-batch barrier (32 blocks) + err publish ----
    if (t == 0) {
      int ei = b * MAX_ITER + it;
      atomicAdd(&errB[ei], sred[0] + sred[1]);
      __threadfence();
      __hip_atomic_fetch_add(&bars[ei], 1, __ATOMIC_ACQ_REL, __HIP_MEMORY_SCOPE_AGENT);
      long long t0c = clock64();
      while (__hip_atomic_load(&bars[ei], __ATOMIC_ACQUIRE,
                               __HIP_MEMORY_SCOPE_AGENT) < 32) {
        __builtin_amdgcn_s_sleep(1);
        if (clock64() - t0c > SPIN_LIMIT) break;
      }
      sred[4] = errB[ei];
    }
    __syncthreads();
    __threadfence();               // acquire peers' partials
    float errb = sred[4];

    // ---- local v' recompute from all 32 slices ----
    {
      const u32* p32 = (const u32*)partials;
      size_t b32 = ((size_t)((((it & 1) << 4) + b) << 5)) << 9;
      #pragma unroll
      for (int h = 0; h < 2; ++h) {
        int idx = (t << 1) + h;
        float t0s = 0.f, t1s = 0.f;
        #pragma unroll
        for (int s = 0; s < 32; ++s) {
          u32 pw = p32[b32 + ((size_t)s << 9) + idx];
          t0s += bf2f((u16)(pw & 0xffffu));
          t1s += bf2f((u16)(pw >> 16));
        }
        vsh[(idx << 1)]     += C_NU24 - flog2(t0s);
        vsh[(idx << 1) + 1] += C_NU24 - flog2(t1s);
      }
    }
    __syncthreads();
    if (errb < ERR_STOP_B) break;  // same-iteration err; update applied (ref freeze)
  }

  // ---- cost: sum 2^(u'+v'-E') * E' / SCALE ----
  float cacc = 0.0f;
  #pragma unroll
  for (int j = 0; j < 32; ++j) {
    float vj = vsh[cbase + (j << 4) + lane15];
    float e0 = (float)epk[j][0][0], e1 = (float)epk[j][0][1];
    float e2 = (float)epk[j][1][0], e3 = (float)epk[j][1][1];
    cacc += fexp2(ur0 + vj - e0) * e0;
    cacc += fexp2(ur1 + vj - e1) * e1;
    cacc += fexp2(ur2 + vj - e2) * e2;
    cacc += fexp2(ur3 + vj - e3) * e3;
  }
  #pragma unroll
  for (int off = 1; off <= 32; off <<= 1) cacc += __shfl_xor(cacc, off);
  if (lane == 0) sred[w] = cacc;
  __syncthreads();
  if (t == 0)
    atomicAdd(&cost[b], (sred[0] + sred[1] + sred[2] + sred[3]) * INV_SCALE_F);
}

// ---------------- fallback path (non-coop; round-4 verified) ----------------
__global__ __launch_bounds__(256) void fb_init(float* __restrict__ v,
                                               float* __restrict__ u_fb,
                                               float* __restrict__ errAcc,
                                               int* __restrict__ done,
                                               float* __restrict__ cost) {
  int g = blockIdx.x * 256 + threadIdx.x;   // 64*256
  if (g < 16384) { v[g] = 0.0f; u_fb[g] = 0.0f; }
  if (g < 128)   errAcc[g] = 0.0f;
  if (g < 16)    cost[g] = 0.0f;
  if (g == 0)    *done = 0;
}

__global__ __launch_bounds__(256) void mfa_gemm_fb(const float* __restrict__ X,
                                                   const float* __restrict__ Y,
                                                   const float* __restrict__ invnx,
                                                   const float* __restrict__ invny,
                                                   half_t* __restrict__ Eh) {
  const int b = blockIdx.z;
  const int rowBase = blockIdx.y * 128, colBase = blockIdx.x * 128;
  const float* Xb = X + (size_t)b * 262144;
  const float* Yb = Y + (size_t)b * 262144;
  __shared__ u16 As[128][72];
  __shared__ u16 Bs[128][72];
  const int t = threadIdx.x;
  const int w = t >> 6, lane = t & 63;
  const int wr = w >> 1, wc = w & 1;
  const int fcol = lane & 15, fk = (lane >> 4) << 3;
  f32x4 acc[4][4];
  #pragma unroll
  for (int i = 0; i < 4; ++i)
    #pragma unroll
    for (int j = 0; j < 4; ++j) acc[i][j] = (f32x4){0.f, 0.f, 0.f, 0.f};
  for (int k0 = 0; k0 < 256; k0 += 64) {
    #pragma unroll
    for (int i = 0; i < 8; ++i) {
      int c = t + (i << 8);
      int row = c >> 4, col = (c & 15) << 2;
      float sA = invnx[(b << 10) + rowBase + row];
      float4 xa = *(const float4*)(Xb + (size_t)(rowBase + row) * 256 + k0 + col);
      ushort4 ua;
      ua.x = f2bf(xa.x * sA); ua.y = f2bf(xa.y * sA);
      ua.z = f2bf(xa.z * sA); ua.w = f2bf(xa.w * sA);
      *(ushort4*)&As[row][col] = ua;
      float sB = invny[(b << 10) + colBase + row];
      float4 ya = *(const float4*)(Yb + (size_t)(colBase + row) * 256 + k0 + col);
      ushort4 ub;
      ub.x = f2bf(ya.x * sB); ub.y = f2bf(ya.y * sB);
      ub.z = f2bf(ya.z * sB); ub.w = f2bf(ya.w * sB);
      *(ushort4*)&Bs[row][col] = ub;
    }
    __syncthreads();
    #pragma unroll
    for (int kk = 0; kk < 64; kk += 32) {
      short8v a[4], bb[4];
      #pragma unroll
      for (int i = 0; i < 4; ++i)
        a[i] = *(const short8v*)&As[wr*64 + i*16 + fcol][kk + fk];
      #pragma unroll
      for (int j = 0; j < 4; ++j)
        bb[j] = *(const short8v*)&Bs[wc*64 + j*16 + fcol][kk + fk];
      #pragma unroll
      for (int i = 0; i < 4; ++i)
        #pragma unroll
        for (int j = 0; j < 4; ++j)
          acc[i][j] = __builtin_amdgcn_mfma_f32_16x16x32_bf16(a[i], bb[j], acc[i][j], 0, 0, 0);
    }
    __syncthreads();
  }
  const int drow4 = (lane >> 4) << 2;
  #pragma unroll
  for (int i = 0; i < 4; ++i)
    #pragma unroll
    for (int j = 0; j < 4; ++j) {
      int col = colBase + wc*64 + j*16 + fcol;
      #pragma unroll
      for (int q = 0; q < 4; ++q) {
        int row = rowBase + wr*64 + i*16 + drow4 + q;
        Eh[(((size_t)(b << 10) + row) << 10) + col] =
            (half_t)((1.0f - acc[i][j][q]) * SCALE_F);
      }
    }
}

__global__ __launch_bounds__(256) void fb_rowpass(const half_t* __restrict__ Eh,
                                                  const float* __restrict__ v,
                                                  float* __restrict__ u,
                                                  float* __restrict__ errAcc,
                                                  const int* __restrict__ done, int it) {
  if (*done) return;
  __shared__ float lred[4];
  const int t = threadIdx.x, w = t >> 6, lane = t & 63;
  const int blk = blockIdx.x, bA = blk >> 5;
  const float4* vb4 = (const float4*)(v + (bA << 10));
  float werr = 0.0f;
  #pragma unroll
  for (int r = 0; r < 8; ++r) {
    const int row = (blk << 5) + (w << 3) + r;
    const half8* E8 = (const half8*)(Eh + ((size_t)row << 10));
    float s = 0.0f;
    #pragma unroll
    for (int q = 0; q < 2; ++q) {
      const int idx = lane + (q << 6);
      half8 e8 = E8[idx];
      float4 p0 = vb4[idx*2], p1 = vb4[idx*2 + 1];
      s += fexp2(p0.x - (float)e8[0]) + fexp2(p0.y - (float)e8[1])
         + fexp2(p0.z - (float)e8[2]) + fexp2(p0.w - (float)e8[3])
         + fexp2(p1.x - (float)e8[4]) + fexp2(p1.y - (float)e8[5])
         + fexp2(p1.z - (float)e8[6]) + fexp2(p1.w - (float)e8[7]);
    }
    #pragma unroll
    for (int off = 32; off; off >>= 1) s += __shfl_xor(s, off);
    if (lane == 0) {
      float unew = C_MU - flog2(s);
      werr += fabsf(unew - u[row]);
      u[row] = unew;
    }
  }
  if (lane == 0) lred[w] = werr;
  __syncthreads();
  if (t == 0) atomicAdd(&errAcc[it], lred[0]+lred[1]+lred[2]+lred[3]);
}

__global__ __launch_bounds__(256) void fb_colpass(const half_t* __restrict__ Eh,
                                                  const float* __restrict__ u,
                                                  u16* __restrict__ partials,
                                                  const int* __restrict__ done) {
  if (*done) return;
  const int t = threadIdx.x, blk = blockIdx.x;
  const int b = blk >> 5, sub = blk & 31;
  const int seg = sub & 15, ct = sub >> 4;
  const int m0 = (ct << 9) + (t << 1);
  const float* ub = u + (b << 10);
  const half_t* Eb = Eh + ((size_t)b << 20);
  float p0 = 0.0f, p1 = 0.0f;
  const int n0 = seg << 6;
  #pragma unroll 4
  for (int n = n0; n < n0 + 64; ++n) {
    float un = ub[n];
    const half_t* e = Eb + ((size_t)n << 10) + m0;
    p0 += fexp2(un - (float)e[0]);
    p1 += fexp2(un - (float)e[1]);
  }
  unsigned packed = (unsigned)f2bf(p0) | ((unsigned)f2bf(p1) << 16);
  *(unsigned*)(partials + ((((b << 4) + seg) << 10) + m0)) = packed;
}

__global__ __launch_bounds__(256) void fb_merge(const u16* __restrict__ partials,
                                                float* __restrict__ v,
                                                const int* __restrict__ done) {
  if (*done) return;
  int g = blockIdx.x * 256 + threadIdx.x;
  const int b = g >> 10, m = g & 1023;
  float tot = 0.0f;
  #pragma unroll
  for (int seg = 0; seg < 16; ++seg)
    tot += bf2f(partials[(((b << 4) + seg) << 10) + m]);
  v[g] = C_NU - flog2(tot);
}

__global__ void fb_check(const float* __restrict__ errAcc, int* __restrict__ done, int it) {
  if (threadIdx.x == 0 && errAcc[it] < ERR_STOP_G) *done = 1;
}

__global__ __launch_bounds__(256) void fb_cost(const half_t* __restrict__ Eh,
                                               const float* __restrict__ u,
                                               const float* __restrict__ v,
                                               float* __restrict__ cost) {
  __shared__ float lred[4];
  const int t = threadIdx.x, w = t >> 6, lane = t & 63;
  const int blk = blockIdx.x, bA = blk >> 5;
  const float4* vb4 = (const float4*)(v + (bA << 10));
  float cacc = 0.0f;
  #pragma unroll
  for (int r = 0; r < 8; ++r) {
    const int row = (blk << 5) + (w << 3) + r;
    const float un = u[row];
    const half8* E8 = (const half8*)(Eh + ((size_t)row << 10));
    #pragma unroll
    for (int q = 0; q < 2; ++q) {
      const int idx = lane + (q << 6);
      half8 e8 = E8[idx];
      float4 p0 = vb4[idx*2], p1 = vb4[idx*2 + 1];
      float e;
      e = (float)e8[0]; cacc += fexp2(un + p0.x - e) * e;
      e = (float)e8[1]; cacc += fexp2(un + p0.y - e) * e;
      e = (float)e8[2]; cacc += fexp2(un + p0.z - e) * e;
      e = (float)e8[3]; cacc += fexp2(un + p0.w - e) * e;
      e = (float)e8[4]; cacc += fexp2(un + p1.x - e) * e;
      e = (float)e8[5]; cacc += fexp2(un + p1.y - e) * e;
      e = (float)e8[6]; cacc += fexp2(un + p1.z - e) * e;
      e = (float)e8[7]; cacc += fexp2(un + p1.w - e) * e;
    }
  }
  #pragma unroll
  for (int off = 32; off; off >>= 1) cacc += __shfl_xor(cacc, off);
  if (lane == 0) lred[w] = cacc;
  __syncthreads();
  if (t == 0) atomicAdd(&cost[blk >> 5],
                        (lred[0]+lred[1]+lred[2]+lred[3]) * INV_SCALE_F);
}

extern "C" void kernel_launch(void* const* d_in, const int* in_sizes, int n_in,
                              void* d_out, int out_size, void* d_ws, size_t ws_size,
                              hipStream_t stream) {
  const float* x = (const float*)d_in[0];
  const float* y = (const float*)d_in[1];
  float* cost = (float*)d_out;

  // region A (32 MB, unioned): main = Xn|Yn|partials ; fallback = Eh
  char* base = (char*)d_ws;
  u16*    Xn       = (u16*)base;                       // 8 MB
  u16*    Yn       = (u16*)(base + 8388608);           // 8 MB
  u16*    partials = (u16*)(base + 16777216);          // 2 MB (parity dbuf)
  half_t* Eh       = (half_t*)base;                    // fb alias: 32 MB
  char* pb = base + 33554432;
  float* errB   = (float*)pb;  pb += 6400;             // 16*100
  int*   bars   = (int*)pb;    pb += 6400;             // 16*100
  float* errAcc = (float*)pb;  pb += 512;              // fb
  int*   done   = (int*)pb;    pb += 64;               // fb
  float* u_fb   = (float*)pb;  pb += 65536;
  float* v_fb   = (float*)pb;  pb += 65536;
  float* invnx  = (float*)pb;  pb += 65536;
  float* invny  = (float*)pb;  pb += 65536;
  u16*   fbpart = (u16*)pb;    pb += 524288;           // fb 16*16*1024
  if ((size_t)(pb - base) > ws_size) return;           // ~34.1 MB needed

  mfa_prep<<<256, 256, 0, stream>>>(x, y, Xn, Yn, invnx, invny, errB, bars, cost);

  const u16* XnC = Xn; const u16* YnC = Yn;
  void* kargs[] = {(void*)&XnC, (void*)&YnC, (void*)&partials,
                   (void*)&errB, (void*)&bars, (void*)&cost};
  hipError_t cerr = hipLaunchCooperativeKernel((const void*)mfa_sink_reg,
                                               dim3(512), dim3(256), kargs, 0, stream);
  if (cerr != hipSuccess) {
    fb_init<<<64, 256, 0, stream>>>(v_fb, u_fb, errAcc, done, cost);
    mfa_gemm_fb<<<dim3(8, 8, 16), 256, 0, stream>>>(x, y, invnx, invny, Eh);
    for (int it = 0; it < MAX_ITER; ++it) {
      fb_rowpass<<<512, 256, 0, stream>>>(Eh, v_fb, u_fb, errAcc, done, it);
      fb_colpass<<<512, 256, 0, stream>>>(Eh, u_fb, fbpart, done);
      fb_merge<<<64, 256, 0, stream>>>(fbpart, v_fb, done);
      fb_check<<<1, 64, 0, stream>>>(errAcc, done, it);
    }
    fb_cost<<<512, 256, 0, stream>>>(Eh, u_fb, v_fb, cost);
  }
}

// Round 6
// 151.521 us; speedup vs baseline: 6.6312x; 6.6312x over previous
//
#include <hip/hip_runtime.h>

typedef _Float16 half_t;
typedef __attribute__((ext_vector_type(8))) _Float16 half8;
typedef __attribute__((ext_vector_type(4))) float f32x4;
typedef __attribute__((ext_vector_type(8))) short short8v;
typedef unsigned short u16;
typedef unsigned int u32;

// Log2-domain scaled math (round-4 verified): E' = (1-cos)*SCALE,
// u',v' are log2 of the real scaling factors.
#define SCALE_F     14.4269504f     /* 10*log2(e) */
#define INV_SCALE_F 0.0693147181f
#define C_MU       -9.99998523f     /* log2(1/1024+1e-8) */
#define C_NU       -9.99998523f
#define MU_F        0.000976572498f /* 2^C_MU */
#define ERR_STOP_B  1.44269504f     /* 0.1 * SCALE, per-batch stop */
#define MAX_ITER    100
#define SPIN_LIMIT  50000000LL

#define SMEM_E   131072             /* 64*1024 fp16 */
#define SMEM_CP  16384              /* 4*1024 f32   */
#define SMEM_V   4096               /* 1024 f32     */
#define SMEM_RED 256
#define SMEM_TOTAL (SMEM_E + SMEM_CP + SMEM_V + SMEM_RED)

__device__ __forceinline__ float fexp2(float x) { return __builtin_amdgcn_exp2f(x); }
__device__ __forceinline__ float flog2(float x) { return __builtin_amdgcn_logf(x); }
__device__ __forceinline__ float frcp(float x)  { return __builtin_amdgcn_rcpf(x); }

__device__ __forceinline__ u16 f2bf(float f) {
  unsigned u = __float_as_uint(f);
  return (u16)((u + 0x7fffu + ((u >> 16) & 1u)) >> 16);
}
__device__ __forceinline__ float bf2f(u16 h) {
  return __uint_as_float(((unsigned)h) << 16);
}

// ---------------- K1: normalize x,y -> bf16 rows; zero per-call state ------
__global__ __launch_bounds__(256) void mfa_prep(const float* __restrict__ x,
                                                const float* __restrict__ y,
                                                u16* __restrict__ Xn,
                                                u16* __restrict__ Yn,
                                                float* __restrict__ errB,
                                                int* __restrict__ bars,
                                                float* __restrict__ cost) {
  int g = blockIdx.x * 256 + threadIdx.x;    // 65536 threads
  if (g < 1600) { errB[g] = 0.0f; bars[g] = 0; }
  if (g < 16)   cost[g] = 0.0f;

  int wid = g >> 6;                          // 0..1023 waves
  int lane = threadIdx.x & 63;
  for (int rr = 0; rr < 32; ++rr) {
    int row = wid + (rr << 10);              // 0..32767
    const float* src = (row < 16384) ? x + (size_t)row * 256
                                     : y + (size_t)(row - 16384) * 256;
    float4 xa = ((const float4*)src)[lane];
    float ss = xa.x*xa.x + xa.y*xa.y + xa.z*xa.z + xa.w*xa.w;
    #pragma unroll
    for (int off = 32; off; off >>= 1) ss += __shfl_xor(ss, off);
    float inv = 1.0f / fmaxf(sqrtf(ss), 1e-8f);
    ushort4 o;
    o.x = f2bf(xa.x * inv); o.y = f2bf(xa.y * inv);
    o.z = f2bf(xa.z * inv); o.w = f2bf(xa.w * inv);
    u16* dst = ((row < 16384) ? Xn + ((size_t)row << 8)
                              : Yn + ((size_t)(row - 16384) << 8)) + lane * 4;
    *(ushort4*)dst = o;
  }
}

// ---------------- K2: fused MFMA E-build + LDS-resident Sinkhorn ----------
// Plain launch, 256 blocks x 512 thr, 151.8 KB LDS -> 1 block/CU, grid=#CUs
// => all blocks co-resident (watchdog-protected spins regardless).
// block (b = blk>>4, k = blk&15) owns rows [k*64, k*64+64) of batch b.
__global__ __launch_bounds__(512, 1) void mfa_sink_fused(
    const u16* __restrict__ Xn, const u16* __restrict__ Yn,
    u16* __restrict__ partials, float* __restrict__ errB,
    int* __restrict__ bars, float* __restrict__ cost) {
  extern __shared__ char smem[];
  half_t* Els  = (half_t*)smem;                               // [64][1024] E'
  float*  cpb  = (float*)(smem + SMEM_E);                     // [4][1024]
  float*  vsh  = (float*)(smem + SMEM_E + SMEM_CP);           // [1024] v'
  float*  sred = (float*)(smem + SMEM_E + SMEM_CP + SMEM_V);  // [8] + flag

  const int t = threadIdx.x, w = t >> 6, lane = t & 63;
  const int lane15 = lane & 15, lgrp = lane >> 4;
  const int blk = blockIdx.x, b = blk >> 4, k = blk & 15;

  // ---- build E' (64 x 1024 fp16) in LDS via MFMA from bf16 Xn/Yn ----
  // Fragment mapping identical to the round-4-verified GEMM:
  //   A row = base + i*16 + (lane&15), k = ks*32 + (lane>>4)*8 .. +8
  //   C/D:  col = cbase + j*16 + (lane&15), row = i*16 + (lane>>4)*4 + q
  {
    const u16* Xb = Xn + ((size_t)((b << 10) + (k << 6)) << 8);  // 64 rows
    const u16* Yb = Yn + ((size_t)(b << 10) << 8);               // 1024 rows
    const int wcol = w << 7;                 // wave's 128-col slice
    #pragma unroll
    for (int pass = 0; pass < 2; ++pass) {
      const int c0 = wcol + (pass << 6);     // 64-col group
      f32x4 acc[4][4];
      #pragma unroll
      for (int i = 0; i < 4; ++i)
        #pragma unroll
        for (int j = 0; j < 4; ++j) acc[i][j] = (f32x4){0.f, 0.f, 0.f, 0.f};
      for (int ks = 0; ks < 8; ++ks) {
        const int koff = (ks << 5) + (lgrp << 3);
        short8v a[4], bb[4];
        #pragma unroll
        for (int i = 0; i < 4; ++i)
          a[i] = *(const short8v*)(Xb + (((i << 4) + lane15) << 8) + koff);
        #pragma unroll
        for (int j = 0; j < 4; ++j)
          bb[j] = *(const short8v*)(Yb + ((size_t)(c0 + (j << 4) + lane15) << 8) + koff);
        #pragma unroll
        for (int i = 0; i < 4; ++i)
          #pragma unroll
          for (int j = 0; j < 4; ++j)
            acc[i][j] = __builtin_amdgcn_mfma_f32_16x16x32_bf16(a[i], bb[j], acc[i][j], 0, 0, 0);
      }
      #pragma unroll
      for (int i = 0; i < 4; ++i)
        #pragma unroll
        for (int j = 0; j < 4; ++j) {
          const int col = c0 + (j << 4) + lane15;
          #pragma unroll
          for (int q = 0; q < 4; ++q) {
            const int row = (i << 4) + (lgrp << 2) + q;
            Els[(row << 10) + col] = (half_t)((1.0f - acc[i][j][q]) * SCALE_F);
          }
        }
    }
  }
  vsh[t] = 0.0f; vsh[t + 512] = 0.0f;
  __syncthreads();

  float ureg[8];
  #pragma unroll
  for (int r = 0; r < 8; ++r) ureg[r] = 0.0f;

  const int mlo = lane << 3;
  int it = 0;
  for (; it < MAX_ITER; ++it) {
    // ---- load v' ----
    const f32x4* v4 = (const f32x4*)vsh;
    f32x4 va = v4[lane*2], vb = v4[lane*2 + 1];
    f32x4 vc = v4[128 + lane*2], vd = v4[128 + lane*2 + 1];
    float vv[16];
    vv[0]=va.x; vv[1]=va.y; vv[2]=va.z; vv[3]=va.w;
    vv[4]=vb.x; vv[5]=vb.y; vv[6]=vb.z; vv[7]=vb.w;
    vv[8]=vc.x; vv[9]=vc.y; vv[10]=vc.z; vv[11]=vc.w;
    vv[12]=vd.x; vv[13]=vd.y; vv[14]=vd.z; vv[15]=vd.w;

    float colacc[16];
    #pragma unroll
    for (int j = 0; j < 16; ++j) colacc[j] = 0.0f;
    float werr = 0.0f;

    // ---- fused u-update + col-partial accumulation (E' from LDS) ----
    #pragma unroll
    for (int r = 0; r < 8; ++r) {
      const half8* E8 = (const half8*)(Els + (((w << 3) + r) << 10));
      half8 ea = E8[lane], eb = E8[lane + 64];
      float rt[16];
      float s = 0.0f;
      #pragma unroll
      for (int j = 0; j < 8; ++j) { rt[j] = fexp2(vv[j] - (float)ea[j]); s += rt[j]; }
      #pragma unroll
      for (int j = 0; j < 8; ++j) { rt[8+j] = fexp2(vv[8+j] - (float)eb[j]); s += rt[8+j]; }
      #pragma unroll
      for (int off = 32; off; off >>= 1) s += __shfl_xor(s, off);
      float unew = C_MU - flog2(s);
      float eu = MU_F * frcp(s);          // 2^u'
      werr += fabsf(unew - ureg[r]);
      ureg[r] = unew;
      #pragma unroll
      for (int j = 0; j < 16; ++j) colacc[j] += rt[j] * eu;
    }
    if (lane == 0) sred[w] = werr;

    // ---- 8-wave col reduce via cpb[4][1024] ----
    if (w < 4) {
      #pragma unroll
      for (int j = 0; j < 4; ++j) {
        *(f32x4*)&cpb[w*1024 + mlo + 4*j - ((j>=2)?8:0) + ((j>=2)?512:0)] =
            (f32x4){colacc[4*j], colacc[4*j+1], colacc[4*j+2], colacc[4*j+3]};
      }
    }
    __syncthreads();
    if (w >= 4) {
      const int wb = (w - 4) * 1024;
      #pragma unroll
      for (int j = 0; j < 8; ++j) cpb[wb + mlo + j] += colacc[j];
      #pragma unroll
      for (int j = 0; j < 8; ++j) cpb[wb + 512 + mlo + j] += colacc[8 + j];
    }
    __syncthreads();

    // ---- write bf16 partials (parity double-buffer) ----
    const int p = it & 1;
    const size_t pbase = ((size_t)(((p << 4) | b) << 4 | k) << 10);
    {
      float ta = cpb[t] + cpb[1024 + t] + cpb[2048 + t] + cpb[3072 + t];
      float tb = cpb[512 + t] + cpb[1536 + t] + cpb[2560 + t] + cpb[3584 + t];
      partials[pbase + t]       = f2bf(ta);
      partials[pbase + t + 512] = f2bf(tb);
    }
    __syncthreads();   // all partial writes done

    // ---- per-batch barrier (16 blocks) + err publish ----
    if (t == 0) {
      float be = sred[0]+sred[1]+sred[2]+sred[3]+sred[4]+sred[5]+sred[6]+sred[7];
      atomicAdd(&errB[b * MAX_ITER + it], be);
      __threadfence();
      __hip_atomic_fetch_add(&bars[b * MAX_ITER + it], 1, __ATOMIC_ACQ_REL,
                             __HIP_MEMORY_SCOPE_AGENT);
      long long t0c = clock64();
      while (__hip_atomic_load(&bars[b * MAX_ITER + it], __ATOMIC_ACQUIRE,
                               __HIP_MEMORY_SCOPE_AGENT) < 16) {
        __builtin_amdgcn_s_sleep(1);
        if (clock64() - t0c > SPIN_LIMIT) break;
      }
      sred[8] = errB[b * MAX_ITER + it];
    }
    __syncthreads();
    __threadfence();   // acquire peers' partials
    float errb = sred[8];

    // ---- local v' recompute from all 16 partial slices ----
    {
      float t0s = 0.0f, t1s = 0.0f;
      const u32* pw32 = (const u32*)partials;
      const size_t base32 = ((size_t)(((p << 4) | b) << 4) << 9);
      #pragma unroll
      for (int j = 0; j < 16; ++j) {
        u32 pw = pw32[base32 + ((size_t)j << 9) + t];
        t0s += bf2f((u16)(pw & 0xffffu));
        t1s += bf2f((u16)(pw >> 16));
      }
      float v0n = vsh[2*t]     + C_NU - flog2(t0s);
      float v1n = vsh[2*t + 1] + C_NU - flog2(t1s);
      vsh[2*t] = v0n; vsh[2*t + 1] = v1n;
    }
    __syncthreads();

    if (errb < ERR_STOP_B) break;   // per-batch stop, update applied (ref freeze)
  }

  // ---- cost: sum 2^(u'+v'-E') * E' / SCALE ----
  {
    const f32x4* v4 = (const f32x4*)vsh;
    f32x4 va = v4[lane*2], vb = v4[lane*2 + 1];
    f32x4 vc = v4[128 + lane*2], vd = v4[128 + lane*2 + 1];
    float vv[16];
    vv[0]=va.x; vv[1]=va.y; vv[2]=va.z; vv[3]=va.w;
    vv[4]=vb.x; vv[5]=vb.y; vv[6]=vb.z; vv[7]=vb.w;
    vv[8]=vc.x; vv[9]=vc.y; vv[10]=vc.z; vv[11]=vc.w;
    vv[12]=vd.x; vv[13]=vd.y; vv[14]=vd.z; vv[15]=vd.w;
    float cacc = 0.0f;
    #pragma unroll
    for (int r = 0; r < 8; ++r) {
      const half8* E8 = (const half8*)(Els + (((w << 3) + r) << 10));
      half8 ea = E8[lane], eb = E8[lane + 64];
      float un = ureg[r];
      #pragma unroll
      for (int j = 0; j < 8; ++j) {
        float e = (float)ea[j];
        cacc += fexp2(un + vv[j] - e) * e;
      }
      #pragma unroll
      for (int j = 0; j < 8; ++j) {
        float e = (float)eb[j];
        cacc += fexp2(un + vv[8+j] - e) * e;
      }
    }
    #pragma unroll
    for (int off = 32; off; off >>= 1) cacc += __shfl_xor(cacc, off);
    if (lane == 0) sred[w] = cacc;
    __syncthreads();
    if (t == 0)
      atomicAdd(&cost[b], (sred[0]+sred[1]+sred[2]+sred[3]+sred[4]+sred[5]+
                           sred[6]+sred[7]) * INV_SCALE_F);
  }
}

extern "C" void kernel_launch(void* const* d_in, const int* in_sizes, int n_in,
                              void* d_out, int out_size, void* d_ws, size_t ws_size,
                              hipStream_t stream) {
  const float* x = (const float*)d_in[0];
  const float* y = (const float*)d_in[1];
  float* cost = (float*)d_out;

  char* base = (char*)d_ws;
  u16*   Xn       = (u16*)base;                        // 8 MB
  u16*   Yn       = (u16*)(base + 8388608);            // 8 MB
  u16*   partials = (u16*)(base + 16777216);           // 1 MB (parity dbuf)
  char* pb = base + 16777216 + 1048576;
  float* errB = (float*)pb;  pb += 6400;               // 16*100
  int*   bars = (int*)pb;    pb += 6400;               // 16*100
  if ((size_t)(pb - base) > ws_size) return;           // ~17.8 MB needed

  mfa_prep<<<256, 256, 0, stream>>>(x, y, Xn, Yn, errB, bars, cost);

  (void)hipFuncSetAttribute((const void*)mfa_sink_fused,
                            hipFuncAttributeMaxDynamicSharedMemorySize, SMEM_TOTAL);
  mfa_sink_fused<<<dim3(256), dim3(512), SMEM_TOTAL, stream>>>(
      Xn, Yn, partials, errB, bars, cost);
}

// Round 7
// 76.483 us; speedup vs baseline: 13.1371x; 1.9811x over previous
//
#include <hip/hip_runtime.h>

typedef _Float16 half_t;
typedef __attribute__((ext_vector_type(8))) _Float16 half8;
typedef __attribute__((ext_vector_type(4))) float f32x4;
typedef __attribute__((ext_vector_type(8))) short short8v;
typedef unsigned short u16;
typedef unsigned int u32;

// Log2-domain scaled math (round-4/6 verified): E' = (1-cos)*SCALE,
// u',v' are log2 of the real scaling factors.
#define SCALE_F     14.4269504f     /* 10*log2(e) */
#define INV_SCALE_F 0.0693147181f
#define C_MU       -9.99998523f     /* log2(1/1024+1e-8) */
#define C_NU       -9.99998523f
#define MU_F        0.000976572498f /* 2^C_MU */
#define ERR_STOP_B  1.44269504f     /* 0.1 * SCALE, per-batch stop */
#define MAX_ITER    100
#define SPIN_LIMIT  50000000LL

#define SMEM_E   131072             /* 64*1024 fp16 */
#define SMEM_CP  16384              /* 4*1024 f32   */
#define SMEM_V   4096               /* 1024 f32     */
#define SMEM_RED 256
#define SMEM_TOTAL (SMEM_E + SMEM_CP + SMEM_V + SMEM_RED)

#define PSTRIDE  520                /* u32 per partial slice: 512 data + werr + pad */

__device__ __forceinline__ float fexp2(float x) { return __builtin_amdgcn_exp2f(x); }
__device__ __forceinline__ float flog2(float x) { return __builtin_amdgcn_logf(x); }
__device__ __forceinline__ float frcp(float x)  { return __builtin_amdgcn_rcpf(x); }

__device__ __forceinline__ u16 f2bf(float f) {
  unsigned u = __float_as_uint(f);
  return (u16)((u + 0x7fffu + ((u >> 16) & 1u)) >> 16);
}
__device__ __forceinline__ float bf2f(u16 h) {
  return __uint_as_float(((unsigned)h) << 16);
}

// ---------------- K1: normalize x,y -> bf16 rows; zero per-call state ------
__global__ __launch_bounds__(256) void mfa_prep(const float* __restrict__ x,
                                                const float* __restrict__ y,
                                                u16* __restrict__ Xn,
                                                u16* __restrict__ Yn,
                                                int* __restrict__ epoch,
                                                float* __restrict__ cost) {
  int g = blockIdx.x * 256 + threadIdx.x;    // 65536 threads
  if (g < 256) epoch[g] = 0;
  if (g < 16)  cost[g] = 0.0f;

  int wid = g >> 6;                          // 0..1023 waves
  int lane = threadIdx.x & 63;
  for (int rr = 0; rr < 32; ++rr) {
    int row = wid + (rr << 10);              // 0..32767
    const float* src = (row < 16384) ? x + (size_t)row * 256
                                     : y + (size_t)(row - 16384) * 256;
    float4 xa = ((const float4*)src)[lane];
    float ss = xa.x*xa.x + xa.y*xa.y + xa.z*xa.z + xa.w*xa.w;
    #pragma unroll
    for (int off = 32; off; off >>= 1) ss += __shfl_xor(ss, off);
    float inv = 1.0f / fmaxf(sqrtf(ss), 1e-8f);
    ushort4 o;
    o.x = f2bf(xa.x * inv); o.y = f2bf(xa.y * inv);
    o.z = f2bf(xa.z * inv); o.w = f2bf(xa.w * inv);
    u16* dst = ((row < 16384) ? Xn + ((size_t)row << 8)
                              : Yn + ((size_t)(row - 16384) << 8)) + lane * 4;
    *(ushort4*)dst = o;
  }
}

// ---------------- K2: fused MFMA E-build + LDS-resident Sinkhorn ----------
// Plain launch, 256 blocks x 512 thr, 151.8 KB LDS -> 1 block/CU.
// XCD-aware remap: all 16 blocks of a batch land on one XCD (perf heuristic;
// correctness uses device-scope atomics regardless of placement).
__global__ __launch_bounds__(512, 1) void mfa_sink_fused(
    const u16* __restrict__ Xn, const u16* __restrict__ Yn,
    u32* __restrict__ partials, int* __restrict__ epoch,
    float* __restrict__ cost) {
  extern __shared__ char smem[];
  half_t* Els  = (half_t*)smem;                               // [64][1024] E'
  float*  cpb  = (float*)(smem + SMEM_E);                     // [4][1024]
  float*  vsh  = (float*)(smem + SMEM_E + SMEM_CP);           // [1024] v'
  float*  sred = (float*)(smem + SMEM_E + SMEM_CP + SMEM_V);  // [8] + err slot

  const int t = threadIdx.x, w = t >> 6, lane = t & 63;
  const int lane15 = lane & 15, lgrp = lane >> 4;
  const int blk = blockIdx.x;
  // XCD grouping: xcd = blk&7 (round-robin heuristic), 2 batches per XCD.
  const int b = ((blk & 7) << 1) | ((blk >> 7) & 1);
  const int k = (blk >> 3) & 15;

  // ---- build E' (64 x 1024 fp16) in LDS via MFMA from bf16 Xn/Yn ----
  {
    const u16* Xb = Xn + ((size_t)((b << 10) + (k << 6)) << 8);  // 64 rows
    const u16* Yb = Yn + ((size_t)(b << 10) << 8);               // 1024 rows
    const int wcol = w << 7;                 // wave's 128-col slice
    #pragma unroll
    for (int pass = 0; pass < 2; ++pass) {
      const int c0 = wcol + (pass << 6);     // 64-col group
      f32x4 acc[4][4];
      #pragma unroll
      for (int i = 0; i < 4; ++i)
        #pragma unroll
        for (int j = 0; j < 4; ++j) acc[i][j] = (f32x4){0.f, 0.f, 0.f, 0.f};
      for (int ks = 0; ks < 8; ++ks) {
        const int koff = (ks << 5) + (lgrp << 3);
        short8v a[4], bb[4];
        #pragma unroll
        for (int i = 0; i < 4; ++i)
          a[i] = *(const short8v*)(Xb + (((i << 4) + lane15) << 8) + koff);
        #pragma unroll
        for (int j = 0; j < 4; ++j)
          bb[j] = *(const short8v*)(Yb + ((size_t)(c0 + (j << 4) + lane15) << 8) + koff);
        #pragma unroll
        for (int i = 0; i < 4; ++i)
          #pragma unroll
          for (int j = 0; j < 4; ++j)
            acc[i][j] = __builtin_amdgcn_mfma_f32_16x16x32_bf16(a[i], bb[j], acc[i][j], 0, 0, 0);
      }
      #pragma unroll
      for (int i = 0; i < 4; ++i)
        #pragma unroll
        for (int j = 0; j < 4; ++j) {
          const int col = c0 + (j << 4) + lane15;
          #pragma unroll
          for (int q = 0; q < 4; ++q) {
            const int row = (i << 4) + (lgrp << 2) + q;
            Els[(row << 10) + col] = (half_t)((1.0f - acc[i][j][q]) * SCALE_F);
          }
        }
    }
  }
  vsh[t] = 0.0f; vsh[t + 512] = 0.0f;
  __syncthreads();

  float ureg[8];
  #pragma unroll
  for (int r = 0; r < 8; ++r) ureg[r] = 0.0f;

  const int mlo = lane << 3;
  int it = 0;
  for (; it < MAX_ITER; ++it) {
    // ---- load v' ----
    const f32x4* v4 = (const f32x4*)vsh;
    f32x4 va = v4[lane*2], vb = v4[lane*2 + 1];
    f32x4 vc = v4[128 + lane*2], vd = v4[128 + lane*2 + 1];
    float vv[16];
    vv[0]=va.x; vv[1]=va.y; vv[2]=va.z; vv[3]=va.w;
    vv[4]=vb.x; vv[5]=vb.y; vv[6]=vb.z; vv[7]=vb.w;
    vv[8]=vc.x; vv[9]=vc.y; vv[10]=vc.z; vv[11]=vc.w;
    vv[12]=vd.x; vv[13]=vd.y; vv[14]=vd.z; vv[15]=vd.w;

    float colacc[16];
    #pragma unroll
    for (int j = 0; j < 16; ++j) colacc[j] = 0.0f;
    float werr = 0.0f;

    // ---- fused u-update + col-partial accumulation (E' from LDS) ----
    #pragma unroll
    for (int r = 0; r < 8; ++r) {
      const half8* E8 = (const half8*)(Els + (((w << 3) + r) << 10));
      half8 ea = E8[lane], eb = E8[lane + 64];
      float rt[16];
      float s = 0.0f;
      #pragma unroll
      for (int j = 0; j < 8; ++j) { rt[j] = fexp2(vv[j] - (float)ea[j]); s += rt[j]; }
      #pragma unroll
      for (int j = 0; j < 8; ++j) { rt[8+j] = fexp2(vv[8+j] - (float)eb[j]); s += rt[8+j]; }
      #pragma unroll
      for (int off = 32; off; off >>= 1) s += __shfl_xor(s, off);
      float unew = C_MU - flog2(s);
      float eu = MU_F * frcp(s);          // 2^u'
      werr += fabsf(unew - ureg[r]);
      ureg[r] = unew;
      #pragma unroll
      for (int j = 0; j < 16; ++j) colacc[j] += rt[j] * eu;
    }
    if (lane == 0) sred[w] = werr;

    // ---- 8-wave col reduce via cpb[4][1024] ----
    if (w < 4) {
      #pragma unroll
      for (int j = 0; j < 4; ++j) {
        *(f32x4*)&cpb[w*1024 + mlo + 4*j - ((j>=2)?8:0) + ((j>=2)?512:0)] =
            (f32x4){colacc[4*j], colacc[4*j+1], colacc[4*j+2], colacc[4*j+3]};
      }
    }
    __syncthreads();
    if (w >= 4) {
      const int wb = (w - 4) * 1024;
      #pragma unroll
      for (int j = 0; j < 8; ++j) cpb[wb + mlo + j] += colacc[j];
      #pragma unroll
      for (int j = 0; j < 8; ++j) cpb[wb + 512 + mlo + j] += colacc[8 + j];
    }
    __syncthreads();

    // ---- publish partial slice (cols 2t,2t+1 packed bf16) + werr -------
    const int p = it & 1;
    u32* ps = partials + (size_t)((((p << 4) | b) << 4) | k) * PSTRIDE;
    {
      float2 q0 = *(const float2*)&cpb[2*t];
      float2 q1 = *(const float2*)&cpb[1024 + 2*t];
      float2 q2 = *(const float2*)&cpb[2048 + 2*t];
      float2 q3 = *(const float2*)&cpb[3072 + 2*t];
      float ca = q0.x + q1.x + q2.x + q3.x;
      float cb = q0.y + q1.y + q2.y + q3.y;
      u32 packed = (u32)f2bf(ca) | ((u32)f2bf(cb) << 16);
      __hip_atomic_store(&ps[t], packed, __ATOMIC_RELAXED, __HIP_MEMORY_SCOPE_AGENT);
      if (t == 0) {
        float be = sred[0]+sred[1]+sred[2]+sred[3]+sred[4]+sred[5]+sred[6]+sred[7];
        __hip_atomic_store(&ps[512], __float_as_uint(be), __ATOMIC_RELAXED,
                           __HIP_MEMORY_SCOPE_AGENT);
      }
    }
    __syncthreads();   // vmcnt(0) drain: all agent stores complete at IC

    // ---- arrival: own epoch slot (no RMW contention); t0 polls 16 slots --
    if (t == 0) {
      __hip_atomic_store(&epoch[(b << 4) | k], it + 1, __ATOMIC_RELAXED,
                         __HIP_MEMORY_SCOPE_AGENT);
      long long t0c = clock64();
      for (;;) {
        int mn = 0x7fffffff;
        #pragma unroll
        for (int j = 0; j < 16; ++j) {
          int e = __hip_atomic_load(&epoch[(b << 4) | j], __ATOMIC_RELAXED,
                                    __HIP_MEMORY_SCOPE_AGENT);
          mn = min(mn, e);
        }
        if (mn >= it + 1) break;
        __builtin_amdgcn_s_sleep(1);
        if (clock64() - t0c > SPIN_LIMIT) break;
      }
    }
    __syncthreads();

    // ---- v' recompute + werr gather (single IC read round) ----
    {
      const u32* pb32 = partials + (size_t)(((p << 4) | b) << 4) * PSTRIDE;
      float t0s = 0.0f, t1s = 0.0f;
      #pragma unroll
      for (int j = 0; j < 16; ++j) {
        u32 pw = __hip_atomic_load(&pb32[j * PSTRIDE + t], __ATOMIC_RELAXED,
                                   __HIP_MEMORY_SCOPE_AGENT);
        t0s += bf2f((u16)(pw & 0xffffu));
        t1s += bf2f((u16)(pw >> 16));
      }
      float we = 0.0f;
      if (t < 16)
        we = __uint_as_float(__hip_atomic_load(&pb32[t * PSTRIDE + 512],
                                               __ATOMIC_RELAXED,
                                               __HIP_MEMORY_SCOPE_AGENT));
      if (w == 0) {
        #pragma unroll
        for (int off = 8; off; off >>= 1) we += __shfl_xor(we, off);
        if (lane == 0) sred[8] = we;
      }
      float v0n = vsh[2*t]     + C_NU - flog2(t0s);
      float v1n = vsh[2*t + 1] + C_NU - flog2(t1s);
      vsh[2*t] = v0n; vsh[2*t + 1] = v1n;
    }
    __syncthreads();

    if (sred[8] < ERR_STOP_B) break;   // per-batch stop, update applied (ref freeze)
  }

  // ---- cost: sum 2^(u'+v'-E') * E' / SCALE ----
  {
    const f32x4* v4 = (const f32x4*)vsh;
    f32x4 va = v4[lane*2], vb = v4[lane*2 + 1];
    f32x4 vc = v4[128 + lane*2], vd = v4[128 + lane*2 + 1];
    float vv[16];
    vv[0]=va.x; vv[1]=va.y; vv[2]=va.z; vv[3]=va.w;
    vv[4]=vb.x; vv[5]=vb.y; vv[6]=vb.z; vv[7]=vb.w;
    vv[8]=vc.x; vv[9]=vc.y; vv[10]=vc.z; vv[11]=vc.w;
    vv[12]=vd.x; vv[13]=vd.y; vv[14]=vd.z; vv[15]=vd.w;
    float cacc = 0.0f;
    #pragma unroll
    for (int r = 0; r < 8; ++r) {
      const half8* E8 = (const half8*)(Els + (((w << 3) + r) << 10));
      half8 ea = E8[lane], eb = E8[lane + 64];
      float un = ureg[r];
      #pragma unroll
      for (int j = 0; j < 8; ++j) {
        float e = (float)ea[j];
        cacc += fexp2(un + vv[j] - e) * e;
      }
      #pragma unroll
      for (int j = 0; j < 8; ++j) {
        float e = (float)eb[j];
        cacc += fexp2(un + vv[8+j] - e) * e;
      }
    }
    #pragma unroll
    for (int off = 32; off; off >>= 1) cacc += __shfl_xor(cacc, off);
    if (lane == 0) sred[w] = cacc;
    __syncthreads();
    if (t == 0)
      atomicAdd(&cost[b], (sred[0]+sred[1]+sred[2]+sred[3]+sred[4]+sred[5]+
                           sred[6]+sred[7]) * INV_SCALE_F);
  }
}

extern "C" void kernel_launch(void* const* d_in, const int* in_sizes, int n_in,
                              void* d_out, int out_size, void* d_ws, size_t ws_size,
                              hipStream_t stream) {
  const float* x = (const float*)d_in[0];
  const float* y = (const float*)d_in[1];
  float* cost = (float*)d_out;

  char* base = (char*)d_ws;
  u16* Xn       = (u16*)base;                          // 8 MB
  u16* Yn       = (u16*)(base + 8388608);              // 8 MB
  u32* partials = (u32*)(base + 16777216);             // 2*16*16*520*4 B
  char* pb = base + 16777216 + (size_t)2*16*16*PSTRIDE*4;
  int* epoch = (int*)pb;  pb += 256 * 4;
  if ((size_t)(pb - base) > ws_size) return;           // ~17.8 MB needed

  mfa_prep<<<256, 256, 0, stream>>>(x, y, Xn, Yn, epoch, cost);

  (void)hipFuncSetAttribute((const void*)mfa_sink_fused,
                            hipFuncAttributeMaxDynamicSharedMemorySize, SMEM_TOTAL);
  mfa_sink_fused<<<dim3(256), dim3(512), SMEM_TOTAL, stream>>>(
      Xn, Yn, partials, epoch, cost);
}